// Round 1
// baseline (142.409 us; speedup 1.0000x reference)
//
#include <hip/hip_runtime.h>
#include <hip/hip_bf16.h>

// Problem constants (from reference setup)
#define T_TOT 32768
#define D_DIM 512
#define K_DIM 512
#define NW_C  128
#define B_C   64
#define LMAX_C 1024

// Tile config
#define BM 128
#define BN 128
#define BK 32
#define ROWT (LMAX_C / BM)   // 8
#define COLT (K_DIM / BN)    // 4
#define SA 40                // padded LDS stride (bf16 elems), 80B = 16B aligned
#define SB 40

typedef __attribute__((ext_vector_type(8))) short bf16x8;
typedef __attribute__((ext_vector_type(4))) short bf16x4;
typedef __attribute__((ext_vector_type(4))) float f32x4;

__device__ __forceinline__ short f2bf(float f) {
    union { __hip_bfloat16 h; short s; } u;
    u.h = __float2bfloat16(f);
    return u.s;
}

__global__ __launch_bounds__(256) void jbmm_kernel(
    const int* __restrict__ offsets,   // B+1 int32
    const int* __restrict__ index,     // B int32
    const float* __restrict__ jagged,  // T x D
    const float* __restrict__ weight,  // NW x D x K
    const float* __restrict__ bias,    // NW x K
    float* __restrict__ out)           // T x K
{
    __shared__ short As[BM * SA];
    __shared__ short Bs[BN * SB];

    const int bid = blockIdx.x;
    const int b   = bid / (ROWT * COLT);
    const int rt  = (bid / COLT) % ROWT;
    const int ct  = bid % COLT;

    const int start = offsets[b];
    const int end   = offsets[b + 1];
    const int m0    = start + rt * BM;
    if (m0 >= end) return;
    const int rows = (end - m0) < BM ? (end - m0) : BM;

    const int idxw = index[b];
    const float* W = weight + (size_t)idxw * D_DIM * K_DIM;
    const int n0 = ct * BN;

    const int tid  = threadIdx.x;
    const int lane = tid & 63;
    const int wid  = tid >> 6;
    const int wr   = wid >> 1;   // 0..1  (wave row in 2x2)
    const int wc   = wid & 1;    // 0..1  (wave col)
    const int lr   = lane & 15;  // fragment row/col index
    const int lg   = lane >> 4;  // 0..3  lane group

    // bias preload (one value per n-fragment)
    float bias_v[4];
#pragma unroll
    for (int ni = 0; ni < 4; ++ni)
        bias_v[ni] = bias[(size_t)idxw * K_DIM + n0 + wc * 64 + ni * 16 + lr];

    f32x4 acc[4][4];
#pragma unroll
    for (int mi = 0; mi < 4; ++mi)
#pragma unroll
        for (int ni = 0; ni < 4; ++ni)
            acc[mi][ni] = (f32x4){0.f, 0.f, 0.f, 0.f};

    // Staging thread maps
    const int col4a = tid & 7;   // which float4 within the 32-wide A row (8 per row)
    const int rowa  = tid >> 3;  // A row 0..31, +32*i
    const int db    = tid & 7;   // weight d-offset 0..7, +8*i
    const int cgb   = tid >> 3;  // weight n col-group (4 floats) 0..31

    for (int k0 = 0; k0 < D_DIM; k0 += BK) {
        // ---- stage A: jagged[m0..m0+127, k0..k0+31] -> As[row][k] (bf16) ----
#pragma unroll
        for (int i = 0; i < 4; ++i) {
            const int r = rowa + 32 * i;
            f32x4 v = (f32x4){0.f, 0.f, 0.f, 0.f};
            if (r < rows)
                v = *reinterpret_cast<const f32x4*>(
                    &jagged[(size_t)(m0 + r) * D_DIM + k0 + col4a * 4]);
            bf16x4 bv;
            bv[0] = f2bf(v[0]); bv[1] = f2bf(v[1]);
            bv[2] = f2bf(v[2]); bv[3] = f2bf(v[3]);
            *reinterpret_cast<bf16x4*>(&As[r * SA + col4a * 4]) = bv;
        }
        // ---- stage B transposed: W[k0+d, n0+n] -> Bs[n][d] (bf16) ----
#pragma unroll
        for (int i = 0; i < 4; ++i) {
            const int d = db + 8 * i;
            f32x4 v = *reinterpret_cast<const f32x4*>(
                &W[(size_t)(k0 + d) * K_DIM + n0 + cgb * 4]);
#pragma unroll
            for (int j = 0; j < 4; ++j)
                Bs[(cgb * 4 + j) * SB + d] = f2bf(v[j]);
        }
        __syncthreads();

        // ---- fragments + MFMA ----
        bf16x8 af[4], bfr[4];
#pragma unroll
        for (int mi = 0; mi < 4; ++mi)
            af[mi] = *reinterpret_cast<bf16x8*>(
                &As[(wr * 64 + mi * 16 + lr) * SA + lg * 8]);
#pragma unroll
        for (int ni = 0; ni < 4; ++ni)
            bfr[ni] = *reinterpret_cast<bf16x8*>(
                &Bs[(wc * 64 + ni * 16 + lr) * SB + lg * 8]);
#pragma unroll
        for (int mi = 0; mi < 4; ++mi)
#pragma unroll
            for (int ni = 0; ni < 4; ++ni)
                acc[mi][ni] = __builtin_amdgcn_mfma_f32_16x16x32_bf16(
                    af[mi], bfr[ni], acc[mi][ni], 0, 0, 0);
        __syncthreads();
    }

    // ---- epilogue: C/D layout col=lane&15, row=(lane>>4)*4+r ----
#pragma unroll
    for (int mi = 0; mi < 4; ++mi) {
        const int rloc = wr * 64 + mi * 16 + lg * 4;
#pragma unroll
        for (int r = 0; r < 4; ++r) {
            const int rr = rloc + r;
            if (rr < rows) {
#pragma unroll
                for (int ni = 0; ni < 4; ++ni) {
                    out[(size_t)(m0 + rr) * K_DIM + n0 + wc * 64 + ni * 16 + lr] =
                        acc[mi][ni][r] + bias_v[ni];
                }
            }
        }
    }
}

extern "C" void kernel_launch(void* const* d_in, const int* in_sizes, int n_in,
                              void* d_out, int out_size, void* d_ws, size_t ws_size,
                              hipStream_t stream) {
    const int*   offsets = (const int*)d_in[1];
    const int*   index   = (const int*)d_in[2];
    const float* jagged  = (const float*)d_in[3];
    const float* weight  = (const float*)d_in[4];
    const float* bias    = (const float*)d_in[5];
    float*       out     = (float*)d_out;

    dim3 grid(B_C * ROWT * COLT);   // 2048 blocks, early-exit on empty row tiles
    dim3 block(256);
    hipLaunchKernelGGL(jbmm_kernel, grid, block, 0, stream,
                       offsets, index, jagged, weight, bias, out);
}

// Round 2
// 83.419 us; speedup vs baseline: 1.7072x; 1.7072x over previous
//
#include <hip/hip_runtime.h>
#include <hip/hip_bf16.h>

// Problem constants
#define D_DIM 512
#define K_DIM 512
#define B_C   64
#define LMAX_C 1024

// Tile config
#define BM 128
#define BN 128
#define BK 64
#define KSTEPS (D_DIM / BK)  // 8
#define ROWT (LMAX_C / BM)   // 8
#define COLT (K_DIM / BN)    // 4
#define SB 72                // padded LDS stride (bf16 elems); 144B rows -> only 2-way bank aliasing (free)

typedef __attribute__((ext_vector_type(8))) short bf16x8;
typedef __attribute__((ext_vector_type(4))) short bf16x4;
typedef __attribute__((ext_vector_type(4))) float f32x4;

__device__ __forceinline__ short f2bf(float f) {
    union { __hip_bfloat16 h; short s; } u;
    u.h = __float2bfloat16(f);
    return u.s;
}

__global__ __launch_bounds__(256) void jbmm_kernel(
    const int* __restrict__ offsets,   // B+1
    const int* __restrict__ index,     // B
    const float* __restrict__ jagged,  // T x D
    const float* __restrict__ weight,  // NW x D x K
    const float* __restrict__ bias,    // NW x K
    float* __restrict__ out)           // T x K
{
    __shared__ short As[BM * SB];
    __shared__ short Bs[BN * SB];

    const int bid = blockIdx.x;
    const int b   = bid / (ROWT * COLT);
    const int rt  = (bid / COLT) % ROWT;
    const int ct  = bid % COLT;

    const int start = offsets[b];
    const int end   = offsets[b + 1];
    const int m0    = start + rt * BM;
    if (m0 >= end) return;
    const int rows = (end - m0) < BM ? (end - m0) : BM;

    const int idxw = index[b];
    const float* W = weight + (size_t)idxw * D_DIM * K_DIM;
    const int n0 = ct * BN;

    const int tid  = threadIdx.x;
    const int lane = tid & 63;
    const int wid  = tid >> 6;
    const int wr   = wid >> 1;   // wave row (2x2)
    const int wc   = wid & 1;    // wave col
    const int lr   = lane & 15;
    const int lg   = lane >> 4;

    // --- staging thread maps ---
    // A: thread covers row (tid>>3)+32*i, 8 consecutive floats at col acol8*8
    const int arow  = tid >> 3;  // 0..31
    const int acol8 = tid & 7;   // 0..7
    // B: per wave, lane covers d-quad dq (0..15) x n-quad nq (0..3); 2 reps over n16
    const int dq = lane >> 2;    // 0..15
    const int nq = lane & 3;     // 0..3

    // bias preload
    float bias_v[4];
#pragma unroll
    for (int ni = 0; ni < 4; ++ni)
        bias_v[ni] = bias[(size_t)idxw * K_DIM + n0 + wc * 64 + ni * 16 + lr];

    f32x4 acc[4][4];
#pragma unroll
    for (int mi = 0; mi < 4; ++mi)
#pragma unroll
        for (int ni = 0; ni < 4; ++ni)
            acc[mi][ni] = (f32x4){0.f, 0.f, 0.f, 0.f};

    f32x4 aR[8];   // A prefetch regs: 4 rows x 2 f32x4
    f32x4 bR[8];   // B prefetch regs: 2 reps x 4 d-rows

#define LOADA(k0_)                                                          \
    {                                                                       \
        _Pragma("unroll")                                                   \
        for (int i = 0; i < 4; ++i) {                                       \
            const int r = arow + 32 * i;                                    \
            f32x4 v0 = (f32x4){0.f,0.f,0.f,0.f};                            \
            f32x4 v1 = (f32x4){0.f,0.f,0.f,0.f};                            \
            if (r < rows) {                                                 \
                const float* p = &jagged[(size_t)(m0 + r) * D_DIM + (k0_) + acol8 * 8]; \
                v0 = *reinterpret_cast<const f32x4*>(p);                    \
                v1 = *reinterpret_cast<const f32x4*>(p + 4);                \
            }                                                               \
            aR[2 * i] = v0; aR[2 * i + 1] = v1;                             \
        }                                                                   \
    }

#define LOADB(k0_)                                                          \
    {                                                                       \
        _Pragma("unroll")                                                   \
        for (int rep = 0; rep < 2; ++rep) {                                 \
            const int n = n0 + (wid * 2 + rep) * 16 + nq * 4;               \
            _Pragma("unroll")                                               \
            for (int i = 0; i < 4; ++i)                                     \
                bR[rep * 4 + i] = *reinterpret_cast<const f32x4*>(          \
                    &W[(size_t)((k0_) + dq * 4 + i) * K_DIM + n]);          \
        }                                                                   \
    }

#define STORE_LDS()                                                         \
    {                                                                       \
        _Pragma("unroll")                                                   \
        for (int i = 0; i < 4; ++i) {                                       \
            const int r = arow + 32 * i;                                    \
            bf16x8 w;                                                       \
            w[0] = f2bf(aR[2*i][0]); w[1] = f2bf(aR[2*i][1]);               \
            w[2] = f2bf(aR[2*i][2]); w[3] = f2bf(aR[2*i][3]);               \
            w[4] = f2bf(aR[2*i+1][0]); w[5] = f2bf(aR[2*i+1][1]);           \
            w[6] = f2bf(aR[2*i+1][2]); w[7] = f2bf(aR[2*i+1][3]);           \
            *reinterpret_cast<bf16x8*>(&As[r * SB + acol8 * 8]) = w;        \
        }                                                                   \
        _Pragma("unroll")                                                   \
        for (int rep = 0; rep < 2; ++rep) {                                 \
            const int nb = (wid * 2 + rep) * 16 + nq * 4;                   \
            _Pragma("unroll")                                               \
            for (int j = 0; j < 4; ++j) {                                   \
                bf16x4 tv;                                                  \
                tv[0] = f2bf(bR[rep*4+0][j]); tv[1] = f2bf(bR[rep*4+1][j]); \
                tv[2] = f2bf(bR[rep*4+2][j]); tv[3] = f2bf(bR[rep*4+3][j]); \
                *reinterpret_cast<bf16x4*>(&Bs[(nb + j) * SB + dq * 4]) = tv; \
            }                                                               \
        }                                                                   \
    }

    LOADA(0); LOADB(0);

    for (int t = 0; t < KSTEPS; ++t) {
        STORE_LDS();
        __syncthreads();
        if (t + 1 < KSTEPS) {
            const int knext = (t + 1) * BK;
            LOADA(knext); LOADB(knext);   // in flight across the MFMA section
        }
#pragma unroll
        for (int kh = 0; kh < 2; ++kh) {
            bf16x8 af[4], bfr[4];
#pragma unroll
            for (int mi = 0; mi < 4; ++mi)
                af[mi] = *reinterpret_cast<bf16x8*>(
                    &As[(wr * 64 + mi * 16 + lr) * SB + kh * 32 + lg * 8]);
#pragma unroll
            for (int ni = 0; ni < 4; ++ni)
                bfr[ni] = *reinterpret_cast<bf16x8*>(
                    &Bs[(wc * 64 + ni * 16 + lr) * SB + kh * 32 + lg * 8]);
#pragma unroll
            for (int mi = 0; mi < 4; ++mi)
#pragma unroll
                for (int ni = 0; ni < 4; ++ni)
                    acc[mi][ni] = __builtin_amdgcn_mfma_f32_16x16x32_bf16(
                        af[mi], bfr[ni], acc[mi][ni], 0, 0, 0);
        }
        __syncthreads();
    }

    // epilogue: C/D layout col=lane&15, row=(lane>>4)*4+r
#pragma unroll
    for (int mi = 0; mi < 4; ++mi) {
        const int rloc = wr * 64 + mi * 16 + lg * 4;
#pragma unroll
        for (int r = 0; r < 4; ++r) {
            const int rr = rloc + r;
            if (rr < rows) {
#pragma unroll
                for (int ni = 0; ni < 4; ++ni) {
                    out[(size_t)(m0 + rr) * K_DIM + n0 + wc * 64 + ni * 16 + lr] =
                        acc[mi][ni][r] + bias_v[ni];
                }
            }
        }
    }
}

extern "C" void kernel_launch(void* const* d_in, const int* in_sizes, int n_in,
                              void* d_out, int out_size, void* d_ws, size_t ws_size,
                              hipStream_t stream) {
    const int*   offsets = (const int*)d_in[1];
    const int*   index   = (const int*)d_in[2];
    const float* jagged  = (const float*)d_in[3];
    const float* weight  = (const float*)d_in[4];
    const float* bias    = (const float*)d_in[5];
    float*       out     = (float*)d_out;

    dim3 grid(B_C * ROWT * COLT);   // 2048 blocks, early-exit on empty row tiles
    dim3 block(256);
    hipLaunchKernelGGL(jbmm_kernel, grid, block, 0, stream,
                       offsets, index, jagged, weight, bias, out);
}

// Round 3
// 47.875 us; speedup vs baseline: 2.9746x; 1.7424x over previous
//
#include <hip/hip_runtime.h>
#include <hip/hip_bf16.h>

// Problem constants
#define D_DIM 512
#define K_DIM 512
#define B_C   64
#define LMAX_C 1024

// Tile config
#define BM 128
#define BN 128
#define BK 64
#define KSTEPS (D_DIM / BK)  // 8
#define ROWT (LMAX_C / BM)   // 8
#define COLT (K_DIM / BN)    // 4
#define NWG  (B_C * ROWT * COLT)   // 2048, divisible by 8 XCDs
#define SB 64                // unpadded stride; bank conflicts handled by XOR swizzle

typedef __attribute__((ext_vector_type(8))) short bf16x8;
typedef __attribute__((ext_vector_type(4))) short bf16x4;
typedef __attribute__((ext_vector_type(4))) float f32x4;

__device__ __forceinline__ short f2bf(float f) {
    union { __hip_bfloat16 h; short s; } u;
    u.h = __float2bfloat16(f);
    return u.s;
}

// Swizzled LDS address: row stride 128B; XOR k-byte with (row&7)<<4.
// 16B-granular, bijective within each row; writes are 16B/8B aligned -> legal.
__device__ __forceinline__ short* lds_addr(short* base, int row, int kbyte) {
    return (short*)((char*)base + row * 128 + (kbyte ^ ((row & 7) << 4)));
}

__global__ __launch_bounds__(256) void jbmm_kernel(
    const int* __restrict__ offsets,   // B+1
    const int* __restrict__ index,     // B
    const float* __restrict__ jagged,  // T x D
    const float* __restrict__ weight,  // NW x D x K
    const float* __restrict__ bias,    // NW x K
    float* __restrict__ out)           // T x K
{
    __shared__ short As[BM * SB];
    __shared__ short Bs[BN * SB];

    // XCD chunk swizzle: hw assigns launch-index i -> XCD i%8; remap so each
    // XCD gets a contiguous range of logical blocks (same-segment tiles share L2).
    const int bidRaw = blockIdx.x;
    const int bid = (bidRaw & 7) * (NWG / 8) + (bidRaw >> 3);

    const int b   = bid / (ROWT * COLT);
    const int rt  = (bid / COLT) % ROWT;
    const int ct  = bid % COLT;

    const int start = offsets[b];
    const int end   = offsets[b + 1];
    const int m0    = start + rt * BM;
    if (m0 >= end) return;
    const int rows = (end - m0) < BM ? (end - m0) : BM;

    const int idxw = index[b];
    const float* W = weight + (size_t)idxw * D_DIM * K_DIM;
    const int n0 = ct * BN;

    const int tid  = threadIdx.x;
    const int lane = tid & 63;
    const int wid  = tid >> 6;
    const int wr   = wid >> 1;   // wave row (2x2)
    const int wc   = wid & 1;    // wave col
    const int lr   = lane & 15;
    const int lg   = lane >> 4;

    // staging maps
    const int arow  = tid >> 3;  // 0..31
    const int acol8 = tid & 7;   // 0..7
    const int dq = lane >> 2;    // 0..15
    const int nq = lane & 3;     // 0..3

    float bias_v[4];
#pragma unroll
    for (int ni = 0; ni < 4; ++ni)
        bias_v[ni] = bias[(size_t)idxw * K_DIM + n0 + wc * 64 + ni * 16 + lr];

    f32x4 acc[4][4];
#pragma unroll
    for (int mi = 0; mi < 4; ++mi)
#pragma unroll
        for (int ni = 0; ni < 4; ++ni)
            acc[mi][ni] = (f32x4){0.f, 0.f, 0.f, 0.f};

    f32x4 aR[8];
    f32x4 bR[8];

#define LOADA(k0_)                                                          \
    {                                                                       \
        _Pragma("unroll")                                                   \
        for (int i = 0; i < 4; ++i) {                                       \
            const int r = arow + 32 * i;                                    \
            f32x4 v0 = (f32x4){0.f,0.f,0.f,0.f};                            \
            f32x4 v1 = (f32x4){0.f,0.f,0.f,0.f};                            \
            if (r < rows) {                                                 \
                const float* p = &jagged[(size_t)(m0 + r) * D_DIM + (k0_) + acol8 * 8]; \
                v0 = *reinterpret_cast<const f32x4*>(p);                    \
                v1 = *reinterpret_cast<const f32x4*>(p + 4);                \
            }                                                               \
            aR[2 * i] = v0; aR[2 * i + 1] = v1;                             \
        }                                                                   \
    }

#define LOADB(k0_)                                                          \
    {                                                                       \
        _Pragma("unroll")                                                   \
        for (int rep = 0; rep < 2; ++rep) {                                 \
            const int n = n0 + (wid * 2 + rep) * 16 + nq * 4;               \
            _Pragma("unroll")                                               \
            for (int i = 0; i < 4; ++i)                                     \
                bR[rep * 4 + i] = *reinterpret_cast<const f32x4*>(          \
                    &W[(size_t)((k0_) + dq * 4 + i) * K_DIM + n]);          \
        }                                                                   \
    }

#define STORE_LDS()                                                         \
    {                                                                       \
        _Pragma("unroll")                                                   \
        for (int i = 0; i < 4; ++i) {                                       \
            const int r = arow + 32 * i;                                    \
            bf16x8 w;                                                       \
            w[0] = f2bf(aR[2*i][0]); w[1] = f2bf(aR[2*i][1]);               \
            w[2] = f2bf(aR[2*i][2]); w[3] = f2bf(aR[2*i][3]);               \
            w[4] = f2bf(aR[2*i+1][0]); w[5] = f2bf(aR[2*i+1][1]);           \
            w[6] = f2bf(aR[2*i+1][2]); w[7] = f2bf(aR[2*i+1][3]);           \
            *reinterpret_cast<bf16x8*>(lds_addr(As, r, acol8 * 16)) = w;    \
        }                                                                   \
        _Pragma("unroll")                                                   \
        for (int rep = 0; rep < 2; ++rep) {                                 \
            const int nb = (wid * 2 + rep) * 16 + nq * 4;                   \
            _Pragma("unroll")                                               \
            for (int j = 0; j < 4; ++j) {                                   \
                bf16x4 tv;                                                  \
                tv[0] = f2bf(bR[rep*4+0][j]); tv[1] = f2bf(bR[rep*4+1][j]); \
                tv[2] = f2bf(bR[rep*4+2][j]); tv[3] = f2bf(bR[rep*4+3][j]); \
                *reinterpret_cast<bf16x4*>(lds_addr(Bs, nb + j, dq * 8)) = tv; \
            }                                                               \
        }                                                                   \
    }

    LOADA(0); LOADB(0);

    for (int t = 0; t < KSTEPS; ++t) {
        STORE_LDS();
        __syncthreads();
        if (t + 1 < KSTEPS) {
            const int knext = (t + 1) * BK;
            LOADA(knext); LOADB(knext);   // in flight across the MFMA section
        }
#pragma unroll
        for (int kh = 0; kh < 2; ++kh) {
            bf16x8 af[4], bfr[4];
#pragma unroll
            for (int mi = 0; mi < 4; ++mi)
                af[mi] = *reinterpret_cast<bf16x8*>(
                    lds_addr(As, wr * 64 + mi * 16 + lr, kh * 64 + lg * 16));
#pragma unroll
            for (int ni = 0; ni < 4; ++ni)
                bfr[ni] = *reinterpret_cast<bf16x8*>(
                    lds_addr(Bs, wc * 64 + ni * 16 + lr, kh * 64 + lg * 16));
#pragma unroll
            for (int mi = 0; mi < 4; ++mi)
#pragma unroll
                for (int ni = 0; ni < 4; ++ni)
                    acc[mi][ni] = __builtin_amdgcn_mfma_f32_16x16x32_bf16(
                        af[mi], bfr[ni], acc[mi][ni], 0, 0, 0);
        }
        __syncthreads();
    }

    // epilogue: C/D layout col=lane&15, row=(lane>>4)*4+r
#pragma unroll
    for (int mi = 0; mi < 4; ++mi) {
        const int rloc = wr * 64 + mi * 16 + lg * 4;
#pragma unroll
        for (int r = 0; r < 4; ++r) {
            const int rr = rloc + r;
            if (rr < rows) {
#pragma unroll
                for (int ni = 0; ni < 4; ++ni) {
                    out[(size_t)(m0 + rr) * K_DIM + n0 + wc * 64 + ni * 16 + lr] =
                        acc[mi][ni][r] + bias_v[ni];
                }
            }
        }
    }
}

extern "C" void kernel_launch(void* const* d_in, const int* in_sizes, int n_in,
                              void* d_out, int out_size, void* d_ws, size_t ws_size,
                              hipStream_t stream) {
    const int*   offsets = (const int*)d_in[1];
    const int*   index   = (const int*)d_in[2];
    const float* jagged  = (const float*)d_in[3];
    const float* weight  = (const float*)d_in[4];
    const float* bias    = (const float*)d_in[5];
    float*       out     = (float*)d_out;

    dim3 grid(NWG);   // 2048 blocks, early-exit on empty row tiles
    dim3 block(256);
    hipLaunchKernelGGL(jbmm_kernel, grid, block, 0, stream,
                       offsets, index, jagged, weight, bias, out);
}

// Round 4
// 47.658 us; speedup vs baseline: 2.9882x; 1.0046x over previous
//
#include <hip/hip_runtime.h>
#include <hip/hip_bf16.h>

// Problem constants
#define D_DIM 512
#define K_DIM 512
#define B_C   64
#define LMAX_C 1024

// Tile config
#define BM 128
#define BN 128
#define BK 64
#define KSTEPS 8             // D_DIM / BK
#define ROWT 8               // LMAX / BM
#define COLT 4               // K_DIM / BN
#define NWG  (B_C * ROWT * COLT)   // 2048, divisible by 8 XCDs

typedef __attribute__((ext_vector_type(8))) short bf16x8;
typedef __attribute__((ext_vector_type(4))) float f32x4;

__device__ __forceinline__ short f2bf(float f) {
    union { __hip_bfloat16 h; short s; } u;
    u.h = __float2bfloat16(f);
    return u.s;
}

// Unified LDS swizzle. Row stride = 128B (64 bf16). 16B-granular XOR:
//   f(r) = ((r&7) ^ ((r>>2)&7)) << 4
// - A-writes: 8 lanes cover one full 128B row -> conflict-free regardless.
// - B-writes: half-wave writes rows 4*n4+n' (n4 varies) -> (r>>2)&7 spreads 8 slots.
// - frag reads: 16 consecutive rows -> values repeat exactly 2x over 8 slots = natural min.
__device__ __forceinline__ short* lds_addr(short* base, int row, int kbyte) {
    return (short*)((char*)base + row * 128 +
                    (kbyte ^ ((((row & 7) ^ ((row >> 2) & 7))) << 4)));
}

__global__ __launch_bounds__(256, 2) void jbmm_kernel(
    const int* __restrict__ offsets,   // B+1
    const int* __restrict__ index,     // B
    const float* __restrict__ jagged,  // T x D
    const float* __restrict__ weight,  // NW x D x K
    const float* __restrict__ bias,    // NW x K
    float* __restrict__ out)           // T x K
{
    // double-buffered: exactly 64 KiB total
    __shared__ short As[2][BM * BK];
    __shared__ short Bs[2][BN * BK];

    // XCD chunk swizzle (2048 % 8 == 0 -> bijective)
    const int bidRaw = blockIdx.x;
    const int bid = (bidRaw & 7) * (NWG / 8) + (bidRaw >> 3);

    const int b   = bid / (ROWT * COLT);
    const int rt  = (bid / COLT) % ROWT;
    const int ct  = bid % COLT;

    const int start = offsets[b];
    const int end   = offsets[b + 1];
    const int m0    = start + rt * BM;
    if (m0 >= end) return;
    const int rows = (end - m0) < BM ? (end - m0) : BM;

    const int idxw = index[b];
    const float* W = weight + (size_t)idxw * D_DIM * K_DIM;
    const int n0 = ct * BN;

    const int tid  = threadIdx.x;
    const int lane = tid & 63;
    const int wid  = tid >> 6;
    const int wr   = wid >> 1;   // wave row (2x2)
    const int wc   = wid & 1;    // wave col
    const int lr   = lane & 15;
    const int lg   = lane >> 4;

    // staging maps
    const int arow  = tid >> 3;  // 0..31 (+32*i)
    const int acol8 = tid & 7;   // 0..7  -> k-octet
    const int n4    = tid & 31;  // 0..31 -> n-quad (rows 4*n4..+3)
    const int dq8   = tid >> 5;  // 0..7  -> k-octet for B

    float bias_v[4];
#pragma unroll
    for (int ni = 0; ni < 4; ++ni)
        bias_v[ni] = bias[(size_t)idxw * K_DIM + n0 + wc * 64 + ni * 16 + lr];

    f32x4 acc[4][4];
#pragma unroll
    for (int mi = 0; mi < 4; ++mi)
#pragma unroll
        for (int ni = 0; ni < 4; ++ni)
            acc[mi][ni] = (f32x4){0.f, 0.f, 0.f, 0.f};

    f32x4 aR[8];   // A: 4 rows x 32B
    f32x4 bR[8];   // B: 8 k-rows x 16B (4 n)

#define LOADA(k0_)                                                          \
    {                                                                       \
        _Pragma("unroll")                                                   \
        for (int i = 0; i < 4; ++i) {                                       \
            const int r = arow + 32 * i;                                    \
            f32x4 v0 = (f32x4){0.f,0.f,0.f,0.f};                            \
            f32x4 v1 = (f32x4){0.f,0.f,0.f,0.f};                            \
            if (r < rows) {                                                 \
                const float* p = &jagged[(size_t)(m0 + r) * D_DIM + (k0_) + acol8 * 8]; \
                v0 = *reinterpret_cast<const f32x4*>(p);                    \
                v1 = *reinterpret_cast<const f32x4*>(p + 4);                \
            }                                                               \
            aR[2 * i] = v0; aR[2 * i + 1] = v1;                             \
        }                                                                   \
    }

#define LOADB(k0_)                                                          \
    {                                                                       \
        _Pragma("unroll")                                                   \
        for (int j = 0; j < 8; ++j)                                         \
            bR[j] = *reinterpret_cast<const f32x4*>(                        \
                &W[(size_t)((k0_) + dq8 * 8 + j) * K_DIM + n0 + n4 * 4]);   \
    }

#define CVTSTORE(c_)                                                        \
    {                                                                       \
        _Pragma("unroll")                                                   \
        for (int i = 0; i < 4; ++i) {                                       \
            const int r = arow + 32 * i;                                    \
            bf16x8 w;                                                       \
            w[0] = f2bf(aR[2*i][0]); w[1] = f2bf(aR[2*i][1]);               \
            w[2] = f2bf(aR[2*i][2]); w[3] = f2bf(aR[2*i][3]);               \
            w[4] = f2bf(aR[2*i+1][0]); w[5] = f2bf(aR[2*i+1][1]);           \
            w[6] = f2bf(aR[2*i+1][2]); w[7] = f2bf(aR[2*i+1][3]);           \
            *reinterpret_cast<bf16x8*>(lds_addr(&As[c_][0], r, acol8 * 16)) = w; \
        }                                                                   \
        _Pragma("unroll")                                                   \
        for (int np = 0; np < 4; ++np) {                                    \
            bf16x8 w;                                                       \
            w[0] = f2bf(bR[0][np]); w[1] = f2bf(bR[1][np]);                 \
            w[2] = f2bf(bR[2][np]); w[3] = f2bf(bR[3][np]);                 \
            w[4] = f2bf(bR[4][np]); w[5] = f2bf(bR[5][np]);                 \
            w[6] = f2bf(bR[6][np]); w[7] = f2bf(bR[7][np]);                 \
            *reinterpret_cast<bf16x8*>(lds_addr(&Bs[c_][0], n4 * 4 + np, dq8 * 16)) = w; \
        }                                                                   \
    }

#define COMPUTE(c_)                                                         \
    {                                                                       \
        _Pragma("unroll")                                                   \
        for (int kh = 0; kh < 2; ++kh) {                                    \
            bf16x8 af[4], bfr[4];                                           \
            _Pragma("unroll")                                               \
            for (int mi = 0; mi < 4; ++mi)                                  \
                af[mi] = *reinterpret_cast<bf16x8*>(                        \
                    lds_addr(&As[c_][0], wr * 64 + mi * 16 + lr, kh * 64 + lg * 16)); \
            _Pragma("unroll")                                               \
            for (int ni = 0; ni < 4; ++ni)                                  \
                bfr[ni] = *reinterpret_cast<bf16x8*>(                       \
                    lds_addr(&Bs[c_][0], wc * 64 + ni * 16 + lr, kh * 64 + lg * 16)); \
            _Pragma("unroll")                                               \
            for (int mi = 0; mi < 4; ++mi)                                  \
                _Pragma("unroll")                                           \
                for (int ni = 0; ni < 4; ++ni)                              \
                    acc[mi][ni] = __builtin_amdgcn_mfma_f32_16x16x32_bf16(  \
                        af[mi], bfr[ni], acc[mi][ni], 0, 0, 0);             \
        }                                                                   \
    }

    // ---- prologue ----
    LOADA(0); LOADB(0);
    CVTSTORE(0);                       // waits on set-0 loads, fills buf0
    LOADA(BK); LOADB(BK);              // set-1 in flight across compute(0)
    __syncthreads();

    // ---- main loop: one barrier per step ----
#pragma unroll
    for (int t = 0; t < KSTEPS; ++t) {
        COMPUTE(t & 1);
        if (t + 1 < KSTEPS) {
            CVTSTORE((t + 1) & 1);     // consume set t+1 (latency hidden by COMPUTE)
            if (t + 2 < KSTEPS) {
                const int kn = (t + 2) * BK;
                LOADA(kn); LOADB(kn);  // issue set t+2
            }
            __syncthreads();
        }
    }

    // ---- epilogue: C/D layout col=lane&15, row=(lane>>4)*4+r ----
#pragma unroll
    for (int mi = 0; mi < 4; ++mi) {
        const int rloc = wr * 64 + mi * 16 + lg * 4;
#pragma unroll
        for (int r = 0; r < 4; ++r) {
            const int rr = rloc + r;
            if (rr < rows) {
#pragma unroll
                for (int ni = 0; ni < 4; ++ni) {
                    out[(size_t)(m0 + rr) * K_DIM + n0 + wc * 64 + ni * 16 + lr] =
                        acc[mi][ni][r] + bias_v[ni];
                }
            }
        }
    }
}

extern "C" void kernel_launch(void* const* d_in, const int* in_sizes, int n_in,
                              void* d_out, int out_size, void* d_ws, size_t ws_size,
                              hipStream_t stream) {
    const int*   offsets = (const int*)d_in[1];
    const int*   index   = (const int*)d_in[2];
    const float* jagged  = (const float*)d_in[3];
    const float* weight  = (const float*)d_in[4];
    const float* bias    = (const float*)d_in[5];
    float*       out     = (float*)d_out;

    dim3 grid(NWG);
    dim3 block(256);
    hipLaunchKernelGGL(jbmm_kernel, grid, block, 0, stream,
                       offsets, index, jagged, weight, bias, out);
}